// Round 1
// 112.854 us; speedup vs baseline: 2.0338x; 2.0338x over previous
//
#include <hip/hip_runtime.h>
#include <hip/hip_bf16.h>

// MPNN fused pipeline, R14: algebraic reassociation.
//   agg_i = (e_i @ e_i.T / D) @ X  ==  e_i @ ((e_i.T @ X)/D)          [exact in R]
//   agg_i @ Wo_i == e_i @ N_i,  N_i = (e_i.T @ X / D) @ Wo_i  (256x256)
// -> the 137-GFLOP fused_simagg (155us, 67% of runtime, latency-floored at
//    the 128-reg/4-wave bracket) is replaced by two thin GEMMs (4.3 GFLOP).
// Final stage: out = relu([Xbf|e1|e2] @ [Wo0t|N1t|N2t]^T + bo), one K=768 GEMM.
// fp8 sim path removed entirely -> absmax should DROP well below 1.625
// (bf16/fp32-accum everywhere instead of e4m3).
//
// All GEMMs reuse the proven 16B-granule XOR-swizzle (granule g of row r at
// slot g^(r&7) within each 64-col block) + global_load_lds(16B) staging.

typedef short bf16x8  __attribute__((ext_vector_type(8)));
typedef short short4v __attribute__((ext_vector_type(4)));
typedef float f32x4   __attribute__((ext_vector_type(4)));

__device__ inline short f2bf(float x) {                // fp32 -> bf16 RNE
    unsigned u = __builtin_bit_cast(unsigned, x);
    return (short)((u + 0x7fffu + ((u >> 16) & 1u)) >> 16);
}
__device__ inline float bf2f(short b) {
    return __builtin_bit_cast(float, (unsigned)((unsigned short)b) << 16);
}
__device__ inline void cp16_async(const char* g, char* l) {
    __builtin_amdgcn_global_load_lds(
        (const __attribute__((address_space(1))) unsigned int*)g,
        (__attribute__((address_space(3))) unsigned int*)l, 16, 0, 0);
}

// ------------------------------------------------------------------ prep_all
// grid (256,10), block (32,8):
//   y<8    : edge_x fp32 -> bf16 h[:,0:256] (swizzled) + Xt [256][8192] (swizzled).
//   y>=8   : tw<64   -> W1 tile  -> Wt1   (swizzled [n][k], ld 256)
//            tw<128  -> W2 tile  -> Wt2
//            tw<320  -> Wo tile  -> rows 0:256   -> Bt4[:,0:256]  (ld 768)
//                                   rows 256:768 -> Wtoh[:,0:512] (ld 512)
//            tw>=320 -> zero M (2*256*256 fp32) for gemm_nt_red atomics.
__global__ void prep_all(const float* __restrict__ X, short* __restrict__ h,
                         int ldh, short* __restrict__ Xt,
                         const float* __restrict__ W1, const float* __restrict__ W2,
                         const float* __restrict__ Wo,
                         short* __restrict__ Wt1, short* __restrict__ Wt2,
                         short* __restrict__ Wtoh, short* __restrict__ Bt4,
                         float* __restrict__ M)
{
    __shared__ short tile[32][33];
    const int tx = threadIdx.x, ty = threadIdx.y;      // 32 x 8
    if (blockIdx.y < 8) {
        const int r0 = blockIdx.x * 32, c0 = blockIdx.y * 32;
        #pragma unroll
        for (int i = 0; i < 4; ++i) {
            int row = ty + i * 8;
            short b = f2bf(X[(size_t)(r0 + row) * 256 + c0 + tx]);
            tile[row][tx] = b;
            int slot = ((((c0 & 32) + tx) >> 3) ^ ((r0 + row) & 7));
            h[(size_t)(r0 + row) * ldh + (c0 & ~63) + slot * 8 + (tx & 7)] = b;
        }
        __syncthreads();
        #pragma unroll
        for (int i = 0; i < 4; ++i) {
            int row = ty + i * 8;                      // d-local
            int d = c0 + row;
            int slot = ((((r0 & 32) + tx) >> 3) ^ (d & 7));
            Xt[(size_t)d * 8192 + (r0 & ~63) + slot * 8 + (tx & 7)] = tile[tx][row];
        }
    } else {
        int tw = (blockIdx.y - 8) * 256 + blockIdx.x;
        if (tw >= 320) {                               // zero M with idle blocks
            int i0 = (tw - 320) * 256 + ty * 32 + tx;
            for (int i = i0; i < 131072; i += 49152) M[i] = 0.f;
            return;
        }
        const float* src; short* dst; int ldwt, dk0, kx, ny;
        if (tw < 64)       { src = W1; dst = Wt1; ldwt = 256;
                             kx = tw >> 3; ny = tw & 7; dk0 = kx * 32; }
        else if (tw < 128) { int u = tw - 64; src = W2; dst = Wt2; ldwt = 256;
                             kx = u >> 3; ny = u & 7; dk0 = kx * 32; }
        else               { int u = tw - 128; int g = u >> 6; int rem = u & 63;
                             kx = rem >> 3; ny = rem & 7;
                             src = Wo + (size_t)g * 256 * 256;
                             if (g == 0) { dst = Bt4;  ldwt = 768; dk0 = kx * 32; }
                             else        { dst = Wtoh; ldwt = 512;
                                           dk0 = (g - 1) * 256 + kx * 32; } }
        const int k0l = kx * 32, n0 = ny * 32;
        #pragma unroll
        for (int i = 0; i < 4; ++i) {
            int row = ty + i * 8;
            tile[row][tx] = f2bf(src[(size_t)(k0l + row) * 256 + n0 + tx]);
        }
        __syncthreads();
        #pragma unroll
        for (int i = 0; i < 4; ++i) {
            int row = ty + i * 8;
            int n = n0 + row;
            int slot = ((((dk0 & 32) + tx) >> 3) ^ (n & 7));
            dst[(size_t)n * ldwt + (dk0 & ~63) + slot * 8 + (tx & 7)] = tile[tx][row];
        }
    }
}

// -------------------------------------------------------- gemm_bias_relu
// C[m,n] = relu(sum_k A[m,k]*Bt[n,k] + bias[n]).  A and Bt granule-swizzled.
// out_mode 0: fp32 plain store (ldo=256)          -> final GEMM
// out_mode 1: bf16 dual write: e tile -> h cols (256+z*256+n0) swizzled,
//             and transposed -> et[n][8192] swizzled (via LDS tile Ts).
__global__ __launch_bounds__(256, 1)
void gemm_bias_relu(const short* __restrict__ A, int lda,
                    const short* __restrict__ Bt0, const short* __restrict__ Bt1,
                    int K,
                    const float* __restrict__ bias0, const float* __restrict__ bias1,
                    void* __restrict__ out0, void* __restrict__ out1,
                    short* __restrict__ hout, int out_mode)
{
    const short* Bt   = blockIdx.z ? Bt1   : Bt0;
    const float* bias = blockIdx.z ? bias1 : bias0;
    void*        outp = blockIdx.z ? out1  : out0;

    const int m0 = blockIdx.x * 64, n0 = blockIdx.y * 64;
    const int t = threadIdx.x;
    const int w = t >> 6, l = t & 63, lr = l & 15, q = l >> 4;
    const int wub = t & ~63;                   // wave-uniform thread base

    __shared__ __attribute__((aligned(16))) short As[64 * 64];
    __shared__ __attribute__((aligned(16))) short Bs[64 * 64];
    __shared__ __attribute__((aligned(16))) short Ts[64 * 64];   // mode-1 only

    f32x4 acc[4];
    #pragma unroll
    for (int i = 0; i < 4; ++i) acc[i] = f32x4{0.f, 0.f, 0.f, 0.f};

    for (int k0 = 0; k0 < K; k0 += 64) {
        __syncthreads();
        #pragma unroll
        for (int it = 0; it < 2; ++it) {
            int idx = it * 256 + t;
            int r = idx >> 3, s = idx & 7;
            cp16_async((const char*)(Bt + (size_t)(n0 + r) * K + k0) + s * 16,
                       (char*)Bs + (size_t)(it * 256 + wub) * 16);
        }
        #pragma unroll
        for (int it = 0; it < 2; ++it) {
            int idx = it * 256 + t;
            int r = idx >> 3, s = idx & 7;
            cp16_async((const char*)(A + (size_t)(m0 + r) * lda + k0) + s * 16,
                       (char*)As + (size_t)(it * 256 + wub) * 16);
        }
        __syncthreads();
        #pragma unroll
        for (int ks = 0; ks < 2; ++ks) {
            int arow = w * 16 + lr;
            bf16x8 af = *(const bf16x8*)&As[arow * 64 + (((ks*4 + q) ^ (arow & 7)) << 3)];
            #pragma unroll
            for (int nt = 0; nt < 4; ++nt) {
                int brow = nt * 16 + lr;
                bf16x8 bfg = *(const bf16x8*)&Bs[brow * 64 + (((ks*4 + q) ^ (brow & 7)) << 3)];
                acc[nt] = __builtin_amdgcn_mfma_f32_16x16x32_bf16(af, bfg, acc[nt], 0, 0, 0);
            }
        }
    }

    if (out_mode == 0) {
        #pragma unroll
        for (int nt = 0; nt < 4; ++nt)
            #pragma unroll
            for (int r = 0; r < 4; ++r) {
                int m = m0 + w * 16 + q * 4 + r;  // C/D: row = quad*4 + reg
                int n = n0 + nt * 16 + lr;        //      col = lane & 15
                float v = acc[nt][r] + bias[n];
                ((float*)outp)[(size_t)m * 256 + n] = v > 0.f ? v : 0.f;
            }
    } else {
        // e = relu(acc+bias): restage bf16 into As (row-major) and Ts
        // (transposed, granule-swizzled: m-granule gm of row nloc at slot
        // gm^(nloc&7); thread's 4 r-values are m-contiguous -> one b64).
        __syncthreads();                          // K-loop readers done
        #pragma unroll
        for (int nt = 0; nt < 4; ++nt) {
            int nloc = nt * 16 + lr;
            short bb[4];
            #pragma unroll
            for (int r = 0; r < 4; ++r) {
                float v = acc[nt][r] + bias[n0 + nloc];
                bb[r] = f2bf(v > 0.f ? v : 0.f);
                As[(w * 16 + q * 4 + r) * 64 + nloc] = bb[r];
            }
            short4v pk = { bb[0], bb[1], bb[2], bb[3] };
            int gm = w * 2 + (q >> 1);            // m-granule = (w*16+q*4)>>3
            *(short4v*)&Ts[nloc * 64 + ((gm ^ (nloc & 7)) << 3) + (q & 1) * 4] = pk;
        }
        __syncthreads();
        short* et = (short*)outp;
        const int cb = 256 + blockIdx.z * 256 + n0;   // h column-block base
        for (int i = t; i < 512; i += 256) {          // h: 64 rows x 8 granules
            int rl = i >> 3, g = i & 7;
            bf16x8 hv = *(const bf16x8*)&As[rl * 64 + g * 8];
            int m = m0 + rl;
            int slot = g ^ (m & 7);
            *(bf16x8*)(hout + (size_t)m * lda + cb + slot * 8) = hv;
        }
        for (int i = t; i < 512; i += 256) {          // et: Ts slot s -> global slot s
            int nl = i >> 3, s = i & 7;
            bf16x8 tv = *(const bf16x8*)&Ts[nl * 64 + s * 8];
            *(bf16x8*)(et + (size_t)(n0 + nl) * 8192 + m0 + s * 8) = tv;
        }
    }
}

// ---------------------------------------------------------- gemm_nt_red
// M_sim[c,d] += sum_k et[c,k]*Xt[d,k] / 256,  K=8192 split 16 ways,
// fp32 atomicAdd epilogue (M zeroed by prep_all).  grid (4,4,32).
__global__ __launch_bounds__(256, 1)
void gemm_nt_red(const short* __restrict__ A0, const short* __restrict__ A1,
                 const short* __restrict__ Xt, float* __restrict__ M)
{
    const int sim = blockIdx.z & 1, split = blockIdx.z >> 1;
    const short* A = sim ? A1 : A0;
    float* Mo = M + (size_t)sim * 65536;
    const int c0 = blockIdx.x * 64, d0 = blockIdx.y * 64;
    const int t = threadIdx.x;
    const int w = t >> 6, l = t & 63, lr = l & 15, q = l >> 4;
    const int wub = t & ~63;

    __shared__ __attribute__((aligned(16))) short As[64 * 64];
    __shared__ __attribute__((aligned(16))) short Bs[64 * 64];

    f32x4 acc[4];
    #pragma unroll
    for (int i = 0; i < 4; ++i) acc[i] = f32x4{0.f, 0.f, 0.f, 0.f};

    const int kb = split * 512;
    for (int k0 = kb; k0 < kb + 512; k0 += 64) {
        __syncthreads();
        #pragma unroll
        for (int it = 0; it < 2; ++it) {
            int idx = it * 256 + t;
            int r = idx >> 3, s = idx & 7;
            cp16_async((const char*)(Xt + (size_t)(d0 + r) * 8192 + k0) + s * 16,
                       (char*)Bs + (size_t)(it * 256 + wub) * 16);
        }
        #pragma unroll
        for (int it = 0; it < 2; ++it) {
            int idx = it * 256 + t;
            int r = idx >> 3, s = idx & 7;
            cp16_async((const char*)(A + (size_t)(c0 + r) * 8192 + k0) + s * 16,
                       (char*)As + (size_t)(it * 256 + wub) * 16);
        }
        __syncthreads();
        #pragma unroll
        for (int ks = 0; ks < 2; ++ks) {
            int arow = w * 16 + lr;
            bf16x8 af = *(const bf16x8*)&As[arow * 64 + (((ks*4 + q) ^ (arow & 7)) << 3)];
            #pragma unroll
            for (int nt = 0; nt < 4; ++nt) {
                int brow = nt * 16 + lr;
                bf16x8 bfg = *(const bf16x8*)&Bs[brow * 64 + (((ks*4 + q) ^ (brow & 7)) << 3)];
                acc[nt] = __builtin_amdgcn_mfma_f32_16x16x32_bf16(af, bfg, acc[nt], 0, 0, 0);
            }
        }
    }
    #pragma unroll
    for (int nt = 0; nt < 4; ++nt)
        #pragma unroll
        for (int r = 0; r < 4; ++r) {
            int m = c0 + w * 16 + q * 4 + r;
            int n = d0 + nt * 16 + lr;
            atomicAdd(&Mo[(size_t)m * 256 + n], acc[nt][r] * (1.0f / 256.0f));
        }
}

// ---------------------------------------------------------- gemm_small_n
// N_sim^T[n,c] = sum_d Wtoh[n, sim*256+d] * M_sim[c,d]   (K=256)
// A = Wtoh (bf16 swizzled, DMA);  B = M fp32 -> bf16 VGPR-staged into Bs.
// Output written bf16 granule-swizzled into Bt4 cols 256+sim*256+c0.
__global__ __launch_bounds__(256, 1)
void gemm_small_n(const short* __restrict__ Wtoh, const float* __restrict__ M,
                  short* __restrict__ Bt4)
{
    const int sim = blockIdx.z;
    const int n0 = blockIdx.x * 64, c0 = blockIdx.y * 64;
    const int t = threadIdx.x;
    const int w = t >> 6, l = t & 63, lr = l & 15, q = l >> 4;
    const int wub = t & ~63;
    const float* Ms = M + (size_t)sim * 65536;

    __shared__ __attribute__((aligned(16))) short As[64 * 64];
    __shared__ __attribute__((aligned(16))) short Bs[64 * 64];

    f32x4 acc[4];
    #pragma unroll
    for (int i = 0; i < 4; ++i) acc[i] = f32x4{0.f, 0.f, 0.f, 0.f};

    for (int k0 = 0; k0 < 256; k0 += 64) {
        __syncthreads();
        #pragma unroll
        for (int it = 0; it < 2; ++it) {
            int idx = it * 256 + t;
            int r = idx >> 3, s = idx & 7;
            cp16_async((const char*)(Wtoh + (size_t)(n0 + r) * 512 + sim * 256 + k0) + s * 16,
                       (char*)As + (size_t)(it * 256 + wub) * 16);
        }
        for (int i = t; i < 512; i += 256) {      // B: M fp32 -> bf16 swizzled
            int r = i >> 3, g = i & 7;
            const float* mp = Ms + (size_t)(c0 + r) * 256 + k0 + g * 8;
            f32x4 va = *(const f32x4*)mp;
            f32x4 vb = *(const f32x4*)(mp + 4);
            bf16x8 pk;
            pk[0] = f2bf(va[0]); pk[1] = f2bf(va[1]);
            pk[2] = f2bf(va[2]); pk[3] = f2bf(va[3]);
            pk[4] = f2bf(vb[0]); pk[5] = f2bf(vb[1]);
            pk[6] = f2bf(vb[2]); pk[7] = f2bf(vb[3]);
            *(bf16x8*)&Bs[r * 64 + ((g ^ (r & 7)) << 3)] = pk;
        }
        __syncthreads();
        #pragma unroll
        for (int ks = 0; ks < 2; ++ks) {
            int arow = w * 16 + lr;
            bf16x8 af = *(const bf16x8*)&As[arow * 64 + (((ks*4 + q) ^ (arow & 7)) << 3)];
            #pragma unroll
            for (int nt = 0; nt < 4; ++nt) {
                int brow = nt * 16 + lr;
                bf16x8 bfg = *(const bf16x8*)&Bs[brow * 64 + (((ks*4 + q) ^ (brow & 7)) << 3)];
                acc[nt] = __builtin_amdgcn_mfma_f32_16x16x32_bf16(af, bfg, acc[nt], 0, 0, 0);
            }
        }
    }
    // epilogue: restage bf16 tile, write swizzled granules into Bt4
    __syncthreads();
    #pragma unroll
    for (int nt = 0; nt < 4; ++nt)
        #pragma unroll
        for (int r = 0; r < 4; ++r)
            As[(w * 16 + q * 4 + r) * 64 + nt * 16 + lr] = f2bf(acc[nt][r]);
    __syncthreads();
    const int cb = 256 + sim * 256 + c0;
    for (int i = t; i < 512; i += 256) {
        int rl = i >> 3, g = i & 7;
        bf16x8 v = *(const bf16x8*)&As[rl * 64 + g * 8];
        int m = n0 + rl;
        int slot = g ^ (m & 7);
        *(bf16x8*)(Bt4 + (size_t)m * 768 + cb + slot * 8) = v;
    }
}

// ---------------------------------------------------------------- launch
extern "C" void kernel_launch(void* const* d_in, const int* in_sizes, int n_in,
                              void* d_out, int out_size, void* d_ws, size_t ws_size,
                              hipStream_t stream)
{
    const float* edge_x = (const float*)d_in[0];
    const float* W1 = (const float*)d_in[1];
    const float* b1 = (const float*)d_in[2];
    const float* W2 = (const float*)d_in[3];
    const float* b2 = (const float*)d_in[4];
    const float* Wo = (const float*)d_in[5];
    const float* bo = (const float*)d_in[6];

    // workspace layout (26,607,616 B total; js=2 path proved >=29.8 MB avail)
    char* ws = (char*)d_ws;
    short* h    = (short*)ws;                    // [8192][768] bf16 swz  12,582,912
    short* Xt   = (short*)(ws + 12582912);       // [256][8192] bf16 swz   4,194,304
    short* e1t  = (short*)(ws + 16777216);       // [256][8192] bf16 swz   4,194,304
    short* e2t  = (short*)(ws + 20971520);       // [256][8192] bf16 swz   4,194,304
    short* Wt1  = (short*)(ws + 25165824);       // [256][256]  bf16 swz     131,072
    short* Wt2  = (short*)(ws + 25296896);       // [256][256]  bf16 swz     131,072
    short* Wtoh = (short*)(ws + 25427968);       // [256][512]  bf16 swz     262,144
    short* Bt4  = (short*)(ws + 25690112);       // [256][768]  bf16 swz     393,216
    float* M    = (float*)(ws + 26083328);       // [2][256][256] fp32       524,288

    prep_all<<<dim3(256, 10), dim3(32, 8), 0, stream>>>(
        edge_x, h, 768, Xt, W1, W2, Wo, Wt1, Wt2, Wtoh, Bt4, M);

    // e1/e2 = relu(X@Wi+bi): -> h cols 256:768 (swz) + e1t/e2t transposed
    gemm_bias_relu<<<dim3(128, 4, 2), 256, 0, stream>>>(
        h, 768, Wt1, Wt2, 256, b1, b2, e1t, e2t, h, 1);

    // M_i = (e_i^T @ X)/256  (split-K 16, atomic fp32)
    gemm_nt_red<<<dim3(4, 4, 32), 256, 0, stream>>>(e1t, e2t, Xt, M);

    // N_i^T = Wo_i^T @ M_i^T -> Bt4 cols 256:768
    gemm_small_n<<<dim3(4, 4, 2), 256, 0, stream>>>(Wtoh, M, Bt4);

    // out = relu(h @ Bt4^T + bo),  K=768
    gemm_bias_relu<<<dim3(128, 4, 1), 256, 0, stream>>>(
        h, 768, Bt4, Bt4, 768, bo, bo, (float*)d_out, (float*)d_out, nullptr, 0);
}